// Round 8
// baseline (318.955 us; speedup 1.0000x reference)
//
#include <hip/hip_runtime.h>
#include <hip/hip_bf16.h>
#include <stdint.h>

#define N_NODES 50000
#define N_EDGES 800000
#define HIDDEN  128
#define HEADS   4
#define HD      (HEADS*HIDDEN)   // 512
#define NTILES  (N_NODES/16)         // 3125 (exact)

// ---- atomic-free CSR build geometry ----
#define NBUCK   196                  // ceil(50000/256) buckets of dst>>8
#define TILE_H  8192                 // edges per hist/scatter block
#define NBLK_H  ((N_EDGES + TILE_H - 1) / TILE_H)   // 98
#define NBH     (NBUCK * NBLK_H)     // 19208 count-matrix entries
#define SWZ_N   196608               // weight-swizzle thread range
#define SWZ_B   (SWZ_N / 256)        // 768 swizzle blocks; hist blocks follow
#define GEMM_BLKS 512                // gemmc blocks in the fused l0 dispatch

typedef __attribute__((ext_vector_type(8))) short  short8;
typedef __attribute__((ext_vector_type(4))) float  floatx4;
typedef __attribute__((ext_vector_type(2))) float  floatx2;

static __device__ __forceinline__ unsigned short bf16_bits(float f) {
    __hip_bfloat16 h = __float2bfloat16(f);
    union { __hip_bfloat16 b; unsigned short s; } u; u.b = h; return u.s;
}

// leaky_relu(a, 0.2) == max(a, 0.2a); then fast exp
static __device__ __forceinline__ float lexp(float a) {
    return __expf(fmaxf(a, 0.2f * a));
}

// pack 8 fp32 -> short8 of bf16 bits (RTNE, bit-identical to the old prep cast)
static __device__ __forceinline__ short8 packbf8(float4 a, float4 b) {
    short8 s;
    s[0] = (short)bf16_bits(a.x); s[1] = (short)bf16_bits(a.y);
    s[2] = (short)bf16_bits(a.z); s[3] = (short)bf16_bits(a.w);
    s[4] = (short)bf16_bits(b.x); s[5] = (short)bf16_bits(b.y);
    s[6] = (short)bf16_bits(b.z); s[7] = (short)bf16_bits(b.w);
    return s;
}

// ---------------- fp8 e4m3 encode/decode (HW cvt when available) ----------------

#if __has_builtin(__builtin_amdgcn_cvt_pk_fp8_f32) && __has_builtin(__builtin_amdgcn_cvt_pk_f32_fp8)
#define FP8_HW 1
#else
#define FP8_HW 0
static __device__ __forceinline__ unsigned fp8_enc1(float f) {
    unsigned s = __float_as_uint(f) >> 31;
    float a = fabsf(f);
    if (a < 0.0009765625f) return s << 7;
    if (a > 448.f) a = 448.f;
    unsigned ub = __float_as_uint(a) + 0x00080000u;  // round at bit19
    int e = (int)((ub >> 23) & 255) - 120;           // biased-7 exponent
    unsigned m = (ub >> 20) & 7;
    if (e <= 0) {
        int mm = (int)(a * 512.f + 0.5f); if (mm > 7) mm = 7;
        return (s << 7) | (unsigned)mm;
    }
    if (e > 15) { e = 15; m = 7; }
    return (s << 7) | ((unsigned)e << 3) | m;
}
static __device__ __forceinline__ floatx2 fp8_dec_pk(unsigned b2) {
    floatx2 r;
    unsigned b = b2 & 255;
    {
        unsigned s = (b >> 7) & 1, e = (b >> 3) & 15, m = b & 7;
        r.x = (e == 0) ? ((s ? -1.f : 1.f) * (float)m * 0.001953125f)
                       : __uint_as_float((s << 31) | ((e + 120) << 23) | (m << 20));
    }
    b = (b2 >> 8) & 255;
    {
        unsigned s = (b >> 7) & 1, e = (b >> 3) & 15, m = b & 7;
        r.y = (e == 0) ? ((s ? -1.f : 1.f) * (float)m * 0.001953125f)
                       : __uint_as_float((s << 31) | ((e + 120) << 23) | (m << 20));
    }
    return r;
}
#endif

static __device__ __forceinline__ unsigned fp8_pack4(float a, float b, float c, float d) {
#if FP8_HW
    int w = __builtin_amdgcn_cvt_pk_fp8_f32(a, b, 0, false);
    w     = __builtin_amdgcn_cvt_pk_fp8_f32(c, d, w, true);
    return (unsigned)w;
#else
    return fp8_enc1(a) | (fp8_enc1(b) << 8) | (fp8_enc1(c) << 16) | (fp8_enc1(d) << 24);
#endif
}

// packed accumulate: acc2[0..3] += w * decode8(u)   (floatx2 math -> v_pk_fma_f32)
static __device__ __forceinline__ void accf8p(floatx2* acc2, uint2 u, float wt) {
    floatx2 wv = {wt, wt};
#if FP8_HW
    acc2[0] += wv * __builtin_amdgcn_cvt_pk_f32_fp8((int)u.x, false);
    acc2[1] += wv * __builtin_amdgcn_cvt_pk_f32_fp8((int)u.x, true);
    acc2[2] += wv * __builtin_amdgcn_cvt_pk_f32_fp8((int)u.y, false);
    acc2[3] += wv * __builtin_amdgcn_cvt_pk_f32_fp8((int)u.y, true);
#else
    acc2[0] += wv * fp8_dec_pk(u.x);
    acc2[1] += wv * fp8_dec_pk(u.x >> 16);
    acc2[2] += wv * fp8_dec_pk(u.y);
    acc2[3] += wv * fp8_dec_pk(u.y >> 16);
#endif
}

// ---------------- prep: weight swizzle + bucket histogram (x-cast ELIMINATED) ----------------
// GEMMs now read fp32 x directly (each row consumed once; cast-in-kernel is bit-identical).
// blocks [0, SWZ_B): weight swizzle; [SWZ_B, SWZ_B+NBLK_H): per-block LDS histogram of
// dst>>8, RAW counts to bh[bucket*NBLK_H + blk] (bin-major).
// proj_w rows PERMUTED (kr -> (kr&7)*16 + (kr>>3)) to compensate rc's [r][ntl] layout.

__global__ __launch_bounds__(256) void prep_k(
        const float* __restrict__ conv_w, const float* __restrict__ proj_w,
        const float* __restrict__ skip_w,
        unsigned short* __restrict__ cwb, unsigned short* __restrict__ pwb,
        unsigned short* __restrict__ swb,
        const int* __restrict__ dst, int* __restrict__ bh) {
    __shared__ int hh[NBUCK];
    if (blockIdx.x >= SWZ_B) {                   // block-uniform branch: syncthreads safe
        int blk = blockIdx.x - SWZ_B;
        for (int c = threadIdx.x; c < NBUCK; c += 256) hh[c] = 0;
        __syncthreads();
        int e0 = blk * TILE_H;
#pragma unroll
        for (int i = 0; i < TILE_H / 256; ++i) {
            int e = e0 + threadIdx.x + i * 256;
            if (e < N_EDGES) atomicAdd(&hh[dst[e] >> 8], 1);
        }
        __syncthreads();
        for (int c = threadIdx.x; c < NBUCK; c += 256) bh[c * NBLK_H + blk] = hh[c];
        return;
    }
    int o = blockIdx.x * 256 + threadIdx.x;
    const float* B; unsigned short* D; int off, N; bool perm = false;
    if (o < 131072)      { B = conv_w + (o >> 16) * 65536; D = cwb + (o >> 16) * 65536; off = o & 65535; N = 512; }
    else if (o < 163840) { int t = o - 131072; B = proj_w + (t >> 14) * 16384; D = pwb + (t >> 14) * 16384; off = t & 16383; N = 128; perm = true; }
    else                 { int t = o - 163840; B = skip_w + (t >> 14) * 16384; D = swb + (t >> 14) * 16384; off = t & 16383; N = 128; }
    int j = off & 7, r = (off >> 3) & 15, q = (off >> 7) & 3;
    int rest = off >> 9, ntn = N >> 4;
    int nt = rest % ntn, kc = rest / ntn;
    int kr = kc * 32 + q * 8 + j;
    int row = perm ? ((kr & 7) * 16 + (kr >> 3)) : kr;
    D[off] = bf16_bits(B[(size_t)row * N + nt * 16 + r]);
}

// ---------------- gemmc body (templated A dtype; shared by plain and fused-l0) ---------------
// h8 row layout (bytes): [head][r][ntl]; natural channel ntl*16+r at byte r*8+ntl of head slice.

template <bool F32A>
static __device__ __forceinline__ void gemmc_body(
        const void* __restrict__ A, const unsigned short* __restrict__ Bs,
        const float* __restrict__ att_s, const float* __restrict__ att_d,
        unsigned char* __restrict__ h8,
        float* __restrict__ a_src, float* __restrict__ a_dst,
        int mtiles, int bid, int stride) {
    int head = threadIdx.x >> 6;
    int lane = threadIdx.x & 63;
    int r = lane & 15, q = lane >> 4;

    short8 Bf[4][8];
#pragma unroll
    for (int kc = 0; kc < 4; ++kc)
#pragma unroll
        for (int ntl = 0; ntl < 8; ++ntl)
            Bf[kc][ntl] = *(const short8*)((const short*)Bs +
                (((size_t)(kc * 32 + head * 8 + ntl) * 4 + q) * 128 + r * 8));

    float as_r[8], ad_r[8];
#pragma unroll
    for (int ntl = 0; ntl < 8; ++ntl) {
        as_r[ntl] = att_s[head * HIDDEN + ntl * 16 + r];
        ad_r[ntl] = att_d[head * HIDDEN + ntl * 16 + r];
    }

    auto loadA = [&](int mtv, short8* dstv) {
        if constexpr (F32A) {
            const float* Ab = (const float*)A + (size_t)(mtv * 16 + r) * HIDDEN + q * 8;
#pragma unroll
            for (int kc = 0; kc < 4; ++kc) {
                float4 v0 = *(const float4*)(Ab + kc * 32);
                float4 v1 = *(const float4*)(Ab + kc * 32 + 4);
                dstv[kc] = packbf8(v0, v1);
            }
        } else {
            const short* Ab = (const short*)A + (size_t)(mtv * 16 + r) * HIDDEN + q * 8;
#pragma unroll
            for (int kc = 0; kc < 4; ++kc) dstv[kc] = *(const short8*)(Ab + kc * 32);
        }
    };

    int mt = bid;
    short8 av[4];
    if (mt < mtiles) loadA(mt, av);
    while (mt < mtiles) {
        int nmt = mt + stride;
        short8 avn[4];
        if (nmt < mtiles) loadA(nmt, avn);
        int m0 = mt * 16;
        floatx4 acc[8];
#pragma unroll
        for (int i = 0; i < 8; ++i) acc[i] = (floatx4){0.f, 0.f, 0.f, 0.f};
#pragma unroll
        for (int kc = 0; kc < 4; ++kc)
#pragma unroll
            for (int ntl = 0; ntl < 8; ++ntl)
                acc[ntl] = __builtin_amdgcn_mfma_f32_16x16x32_bf16(av[kc], Bf[kc][ntl], acc[ntl], 0, 0, 0);

        // store h8: row q*4+i, 8 B per row per lane
#pragma unroll
        for (int i = 0; i < 4; ++i) {
            uint2 o;
            o.x = fp8_pack4(acc[0][i], acc[1][i], acc[2][i], acc[3][i]);
            o.y = fp8_pack4(acc[4][i], acc[5][i], acc[6][i], acc[7][i]);
            *(uint2*)(h8 + (size_t)(m0 + q * 4 + i) * HD + head * HIDDEN + r * 8) = o;
        }
        // fused alpha (fp32 accumulators — full precision)
        float sA[4] = {0, 0, 0, 0}, sD[4] = {0, 0, 0, 0};
#pragma unroll
        for (int ntl = 0; ntl < 8; ++ntl)
#pragma unroll
            for (int i = 0; i < 4; ++i) {
                sA[i] += acc[ntl][i] * as_r[ntl];
                sD[i] += acc[ntl][i] * ad_r[ntl];
            }
#pragma unroll
        for (int d = 1; d < 16; d <<= 1)
#pragma unroll
            for (int i = 0; i < 4; ++i) {
                sA[i] += __shfl_xor(sA[i], d);
                sD[i] += __shfl_xor(sD[i], d);
            }
        if (r == 0)
#pragma unroll
            for (int i = 0; i < 4; ++i) {
                int row = m0 + q * 4 + i;
                a_src[row * HEADS + head] = sA[i];
                a_dst[row * HEADS + head] = sD[i];
            }
        mt = nmt;
#pragma unroll
        for (int kc = 0; kc < 4; ++kc) av[kc] = avn[kc];
    }
}

__global__ __launch_bounds__(256, 2) void gemmc_k(
        const __hip_bfloat16* __restrict__ A, const unsigned short* __restrict__ Bs,
        const float* __restrict__ att_s, const float* __restrict__ att_d,
        unsigned char* __restrict__ h8,
        float* __restrict__ a_src, float* __restrict__ a_dst, int mtiles) {
    gemmc_body<false>(A, Bs, att_s, att_d, h8, a_src, a_dst, mtiles, blockIdx.x, gridDim.x);
}

// ---------------- fused gemmc-l0 (fp32 A) + scatterA (block-range split) ----------------
// blocks [0, GEMM_BLKS): gemmc reading x fp32 directly.
// blocks [GEMM_BLKS, GEMM_BLKS+NBLK_H): scatter, with redundant scan of RAW bh.

__global__ __launch_bounds__(256, 2) void gemmcsc_k(
        const float* __restrict__ A, const unsigned short* __restrict__ Bs,
        const float* __restrict__ att_s, const float* __restrict__ att_d,
        unsigned char* __restrict__ h8,
        float* __restrict__ a_src, float* __restrict__ a_dst, int mtiles,
        const int* __restrict__ src, const int* __restrict__ dst,
        const int* __restrict__ bh, unsigned* __restrict__ tmp) {
    __shared__ int cnt[256], scanbuf[256];
    if (blockIdx.x < GEMM_BLKS) {
        gemmc_body<true>(A, Bs, att_s, att_d, h8, a_src, a_dst, mtiles, blockIdx.x, GEMM_BLKS);
        return;
    }
    int blk = blockIdx.x - GEMM_BLKS;
    int t = threadIdx.x;
    // redundant scan: thread t owns bucket t (t < NBUCK)
    int Tt = 0, Pt = 0;
    if (t < NBUCK) {
        const int* row = bh + (size_t)t * NBLK_H;
        for (int i = 0; i < NBLK_H; ++i) {
            int v = row[i];
            Tt += v;
            Pt += (i < blk) ? v : 0;
        }
    }
    scanbuf[t] = Tt;
    __syncthreads();
    for (int off = 1; off < 256; off <<= 1) {
        int xv = (t >= off) ? scanbuf[t - off] : 0;
        __syncthreads();
        scanbuf[t] += xv;
        __syncthreads();
    }
    int excl = scanbuf[t] - Tt;           // bucket base (exclusive over buckets)
    if (t < NBUCK) cnt[t] = excl + Pt;    // + within-bucket prefix for this block
    __syncthreads();
    int e0 = blk * TILE_H;
#pragma unroll
    for (int i = 0; i < TILE_H / 256; ++i) {
        int e = e0 + t + i * 256;
        if (e < N_EDGES) {
            int d = dst[e];
            int pos = atomicAdd(&cnt[d >> 8], 1);
            tmp[pos] = ((unsigned)(d & 255) << 16) | (unsigned)src[e];
        }
    }
}

// ---------------- sortB: per-bucket low-byte counting sort + row_ptr ----------------
// One block per bucket. Bucket bases recomputed redundantly from RAW bh.

__global__ __launch_bounds__(256) void sortB_k(const unsigned* __restrict__ tmp,
                                               const int* __restrict__ bh,
                                               int* __restrict__ src_sorted,
                                               int* __restrict__ row_ptr) {
    __shared__ int cnt[256], buf[256], pos[256], bbase[256], btot[256];
    int t = threadIdx.x, b = blockIdx.x;
    // redundant bucket-base scan from raw counts
    int Tt = 0;
    if (t < NBUCK) {
        const int* row = bh + (size_t)t * NBLK_H;
        for (int i = 0; i < NBLK_H; ++i) Tt += row[i];
    }
    buf[t] = Tt;
    __syncthreads();
    for (int off = 1; off < 256; off <<= 1) {
        int xv = (t >= off) ? buf[t - off] : 0;
        __syncthreads();
        buf[t] += xv;
        __syncthreads();
    }
    bbase[t] = buf[t] - Tt;
    btot[t]  = Tt;
    __syncthreads();
    int beg = bbase[b];
    int end = beg + btot[b];
    // low-byte counting sort within bucket
    cnt[t] = 0;
    __syncthreads();
    for (int i = beg + t; i < end; i += 256) atomicAdd(&cnt[(tmp[i] >> 16) & 255], 1);
    __syncthreads();
    int v = cnt[t];
    buf[t] = v;
    __syncthreads();
    for (int off = 1; off < 256; off <<= 1) {
        int xv = (t >= off) ? buf[t - off] : 0;
        __syncthreads();
        buf[t] += xv;
        __syncthreads();
    }
    int excl = buf[t] - v;
    int d = b * 256 + t;
    if (d <= N_NODES) row_ptr[d] = beg + excl;   // d==N_NODES lands on beg+full = N_EDGES
    pos[t] = excl;
    __syncthreads();
    for (int i = beg + t; i < end; i += 256) {
        unsigned w = tmp[i];
        int c = (w >> 16) & 255;
        int p = beg + atomicAdd(&pos[c], 1);
        src_sorted[p] = (int)(w & 0xFFFFu);
    }
}

// ---------------- proj+skip dual GEMM: B-in-regs, A/A2 prefetch; A2 optionally fp32 --------

template <typename OutT, bool F32A2>
__global__ __launch_bounds__(256, 2) void gemmp_k(
        const __hip_bfloat16* __restrict__ A,  const unsigned short* __restrict__ Bs,
        const void* __restrict__ A2, const unsigned short* __restrict__ Bs2,
        const float* __restrict__ b1, const float* __restrict__ b2,
        OutT* __restrict__ D, int mtiles) {
    int wave = threadIdx.x >> 6;
    int lane = threadIdx.x & 63;
    int r = lane & 15, q = lane >> 4;
    int nh = wave & 1;

    short8 Bf[4][4], Bf2[4][4];
#pragma unroll
    for (int kc = 0; kc < 4; ++kc)
#pragma unroll
        for (int ntl = 0; ntl < 4; ++ntl) {
            size_t off = (((size_t)(kc * 8 + nh * 4 + ntl) * 4 + q) * 128 + r * 8);
            Bf[kc][ntl]  = *(const short8*)((const short*)Bs  + off);
            Bf2[kc][ntl] = *(const short8*)((const short*)Bs2 + off);
        }
    float bias[4];
#pragma unroll
    for (int ntl = 0; ntl < 4; ++ntl) {
        int col = nh * 64 + ntl * 16 + r;
        bias[ntl] = b1[col] + b2[col];
    }

    auto loadA = [&](int mtv, short8* d1, short8* d2) {
        const short* Ab = (const short*)A + (size_t)(mtv * 16 + r) * HIDDEN + q * 8;
#pragma unroll
        for (int kc = 0; kc < 4; ++kc) d1[kc] = *(const short8*)(Ab + kc * 32);
        if constexpr (F32A2) {
            const float* Ab2 = (const float*)A2 + (size_t)(mtv * 16 + r) * HIDDEN + q * 8;
#pragma unroll
            for (int kc = 0; kc < 4; ++kc) {
                float4 v0 = *(const float4*)(Ab2 + kc * 32);
                float4 v1 = *(const float4*)(Ab2 + kc * 32 + 4);
                d2[kc] = packbf8(v0, v1);
            }
        } else {
            const short* Ab2 = (const short*)A2 + (size_t)(mtv * 16 + r) * HIDDEN + q * 8;
#pragma unroll
            for (int kc = 0; kc < 4; ++kc) d2[kc] = *(const short8*)(Ab2 + kc * 32);
        }
    };

    const int stride = gridDim.x * 2;
    int mt = blockIdx.x * 2 + (wave >> 1);
    short8 av[4], av2[4];
    if (mt < mtiles) loadA(mt, av, av2);
    while (mt < mtiles) {
        int nmt = mt + stride;
        short8 avn[4], avn2[4];
        if (nmt < mtiles) loadA(nmt, avn, avn2);
        int m0 = mt * 16;
        floatx4 acc[4];
#pragma unroll
        for (int i = 0; i < 4; ++i) acc[i] = (floatx4){0.f, 0.f, 0.f, 0.f};
#pragma unroll
        for (int kc = 0; kc < 4; ++kc)
#pragma unroll
            for (int ntl = 0; ntl < 4; ++ntl) {
                acc[ntl] = __builtin_amdgcn_mfma_f32_16x16x32_bf16(av[kc],  Bf[kc][ntl],  acc[ntl], 0, 0, 0);
                acc[ntl] = __builtin_amdgcn_mfma_f32_16x16x32_bf16(av2[kc], Bf2[kc][ntl], acc[ntl], 0, 0, 0);
            }
#pragma unroll
        for (int ntl = 0; ntl < 4; ++ntl) {
            int col = nh * 64 + ntl * 16 + r;
#pragma unroll
            for (int i = 0; i < 4; ++i) {
                int row = m0 + q * 4 + i;
                float v = acc[ntl][i] + bias[ntl];
                if constexpr (sizeof(OutT) == 4)
                    ((float*)D)[(size_t)row * HIDDEN + col] = v;
                else
                    ((__hip_bfloat16*)D)[(size_t)row * HIDDEN + col] = __float2bfloat16(v);
            }
        }
        mt = nmt;
#pragma unroll
        for (int kc = 0; kc < 4; ++kc) { av[kc] = avn[kc]; av2[kc] = avn2[kc]; }
    }
}

// ---------------- fused softmax + aggregation: TWO nodes per wave ----------------
// Round-0 load structure (wave-uniform edge ids via readlane, 8 B/lane dwordx2 gathers)
// but each wave owns adjacent nodes (n0, n0+1) with SEPARATE accumulator chains:
// the interleaved 4+4 group keeps 8 independent gathers + 8 alpha loads in flight
// (dual dep-chains prevent the compiler's load serialization seen at VGPR=32).
// Adjacent pair shares a row_ptr boundary; epilogue stores both rows concurrently
// (lanes 0-15 -> n0, lanes 16-31 -> n1).

__global__ __launch_bounds__(256) void msg_k(const int* __restrict__ row_ptr,
                                             const int* __restrict__ src_sorted,
                                             const float* __restrict__ a_src,
                                             const float* __restrict__ a_dst,
                                             const unsigned char* __restrict__ h8,
                                             const float* __restrict__ conv_b,
                                             __hip_bfloat16* __restrict__ rc) {
    int wave = threadIdx.x >> 6;
    int lane = threadIdx.x & 63;
    int head = lane >> 4;
    int n0 = (blockIdx.x * 4 + wave) * 2;
    if (n0 >= N_NODES) return;
    int n1 = n0 + 1;                     // N_NODES even -> always valid
    const uint2* hq = (const uint2*)h8;

    float adn0 = a_dst[n0 * HEADS + head];
    float adn1 = a_dst[n1 * HEADS + head];
    int beg0 = row_ptr[n0];
    int end0 = row_ptr[n1];              // shared boundary
    int end1 = row_ptr[n1 + 1];

    floatx2 accA[4], accB[4];
#pragma unroll
    for (int k = 0; k < 4; ++k) { accA[k] = (floatx2){0.f, 0.f}; accB[k] = (floatx2){0.f, 0.f}; }
    float es0 = 0.f, es1 = 0.f;

    int base0 = beg0, base1 = end0;
    while (base0 < end0 || base1 < end1) {
        int m0 = min(32, end0 - base0);
        int m1 = min(32, end1 - base1);
        int sv0 = (lane < m0) ? src_sorted[base0 + lane] : 0;
        int sv1 = (lane < m1) ? src_sorted[base1 + lane] : 0;
        int j0 = 0, j1 = 0;
        // interleaved 4+4: 8 gathers + 8 alpha loads in flight, two dep-chains
        for (; j0 + 4 <= m0 && j1 + 4 <= m1; j0 += 4, j1 += 4) {
            int a0 = __builtin_amdgcn_readlane(sv0, j0);
            int a1 = __builtin_amdgcn_readlane(sv0, j0 + 1);
            int a2 = __builtin_amdgcn_readlane(sv0, j0 + 2);
            int a3 = __builtin_amdgcn_readlane(sv0, j0 + 3);
            int b0 = __builtin_amdgcn_readlane(sv1, j1);
            int b1 = __builtin_amdgcn_readlane(sv1, j1 + 1);
            int b2 = __builtin_amdgcn_readlane(sv1, j1 + 2);
            int b3 = __builtin_amdgcn_readlane(sv1, j1 + 3);
            uint2 uA0 = hq[(size_t)a0 * 64 + lane];
            uint2 uA1 = hq[(size_t)a1 * 64 + lane];
            uint2 uA2 = hq[(size_t)a2 * 64 + lane];
            uint2 uA3 = hq[(size_t)a3 * 64 + lane];
            uint2 uB0 = hq[(size_t)b0 * 64 + lane];
            uint2 uB1 = hq[(size_t)b1 * 64 + lane];
            uint2 uB2 = hq[(size_t)b2 * 64 + lane];
            uint2 uB3 = hq[(size_t)b3 * 64 + lane];
            float eA0 = lexp(a_src[a0 * 4 + head] + adn0);
            float eA1 = lexp(a_src[a1 * 4 + head] + adn0);
            float eA2 = lexp(a_src[a2 * 4 + head] + adn0);
            float eA3 = lexp(a_src[a3 * 4 + head] + adn0);
            float eB0 = lexp(a_src[b0 * 4 + head] + adn1);
            float eB1 = lexp(a_src[b1 * 4 + head] + adn1);
            float eB2 = lexp(a_src[b2 * 4 + head] + adn1);
            float eB3 = lexp(a_src[b3 * 4 + head] + adn1);
            accf8p(accA, uA0, eA0);
            accf8p(accB, uB0, eB0);
            accf8p(accA, uA1, eA1);
            accf8p(accB, uB1, eB1);
            accf8p(accA, uA2, eA2);
            accf8p(accB, uB2, eB2);
            accf8p(accA, uA3, eA3);
            accf8p(accB, uB3, eB3);
            es0 += (eA0 + eA1) + (eA2 + eA3);
            es1 += (eB0 + eB1) + (eB2 + eB3);
        }
        for (; j0 + 4 <= m0; j0 += 4) {
            int a0 = __builtin_amdgcn_readlane(sv0, j0);
            int a1 = __builtin_amdgcn_readlane(sv0, j0 + 1);
            int a2 = __builtin_amdgcn_readlane(sv0, j0 + 2);
            int a3 = __builtin_amdgcn_readlane(sv0, j0 + 3);
            uint2 uA0 = hq[(size_t)a0 * 64 + lane];
            uint2 uA1 = hq[(size_t)a1 * 64 + lane];
            uint2 uA2 = hq[(size_t)a2 * 64 + lane];
            uint2 uA3 = hq[(size_t)a3 * 64 + lane];
            float eA0 = lexp(a_src[a0 * 4 + head] + adn0);
            float eA1 = lexp(a_src[a1 * 4 + head] + adn0);
            float eA2 = lexp(a_src[a2 * 4 + head] + adn0);
            float eA3 = lexp(a_src[a3 * 4 + head] + adn0);
            accf8p(accA, uA0, eA0);
            accf8p(accA, uA1, eA1);
            accf8p(accA, uA2, eA2);
            accf8p(accA, uA3, eA3);
            es0 += (eA0 + eA1) + (eA2 + eA3);
        }
        for (; j1 + 4 <= m1; j1 += 4) {
            int b0 = __builtin_amdgcn_readlane(sv1, j1);
            int b1 = __builtin_amdgcn_readlane(sv1, j1 + 1);
            int b2 = __builtin_amdgcn_readlane(sv1, j1 + 2);
            int b3 = __builtin_amdgcn_readlane(sv1, j1 + 3);
            uint2 uB0 = hq[(size_t)b0 * 64 + lane];
            uint2 uB1 = hq[(size_t)b1 * 64 + lane];
            uint2 uB2 = hq[(size_t)b2 * 64 + lane];
            uint2 uB3 = hq[(size_t)b3 * 64 + lane];
            float eB0 = lexp(a_src[b0 * 4 + head] + adn1);
            float eB1 = lexp(a_src[b1 * 4 + head] + adn1);
            float eB2 = lexp(a_src[b2 * 4 + head] + adn1);
            float eB3 = lexp(a_src[b3 * 4 + head] + adn1);
            accf8p(accB, uB0, eB0);
            accf8p(accB, uB1, eB1);
            accf8p(accB, uB2, eB2);
            accf8p(accB, uB3, eB3);
            es1 += (eB0 + eB1) + (eB2 + eB3);
        }
        for (; j0 < m0; ++j0) {
            int a0 = __builtin_amdgcn_readlane(sv0, j0);
            uint2 uA0 = hq[(size_t)a0 * 64 + lane];
            float eA0 = lexp(a_src[a0 * 4 + head] + adn0);
            accf8p(accA, uA0, eA0);
            es0 += eA0;
        }
        for (; j1 < m1; ++j1) {
            int b0 = __builtin_amdgcn_readlane(sv1, j1);
            uint2 uB0 = hq[(size_t)b0 * 64 + lane];
            float eB0 = lexp(a_src[b0 * 4 + head] + adn1);
            accf8p(accB, uB0, eB0);
            es1 += eB0;
        }
        base0 += m0;
        base1 += m1;
    }

    float r0 = 1.f / (es0 + 1e-16f);
    float r1 = 1.f / (es1 + 1e-16f);
    float fa[8], fb[8];
#pragma unroll
    for (int k = 0; k < 4; ++k) {
        fa[2 * k] = accA[k].x * r0; fa[2 * k + 1] = accA[k].y * r0;
        fb[2 * k] = accB[k].x * r1; fb[2 * k + 1] = accB[k].y * r1;
    }
#pragma unroll
    for (int k = 0; k < 8; ++k) {
        fa[k] += __shfl_xor(fa[k], 16);
        fa[k] += __shfl_xor(fa[k], 32);
        fb[k] += __shfl_xor(fb[k], 16);
        fb[k] += __shfl_xor(fb[k], 32);
    }
    if (lane < 16) {
        union { uint4 v; unsigned short us[8]; } o;
#pragma unroll
        for (int k = 0; k < 8; ++k) {
            float mres = 0.25f * fa[k] + conv_b[k * 16 + lane];
            o.us[k] = bf16_bits(mres > 0.f ? mres : 0.f);
        }
        ((uint4*)rc)[(size_t)n0 * 16 + lane] = o.v;
    } else if (lane < 32) {
        int rr = lane & 15;
        union { uint4 v; unsigned short us[8]; } o;
#pragma unroll
        for (int k = 0; k < 8; ++k) {
            float mres = 0.25f * fb[k] + conv_b[k * 16 + rr];
            o.us[k] = bf16_bits(mres > 0.f ? mres : 0.f);
        }
        ((uint4*)rc)[(size_t)n1 * 16 + rr] = o.v;
    }
}

// ---------------- launcher ----------------

extern "C" void kernel_launch(void* const* d_in, const int* in_sizes, int n_in,
                              void* d_out, int out_size, void* d_ws, size_t ws_size,
                              hipStream_t stream) {
    const float* x      = (const float*)d_in[0];
    const int*   ei     = (const int*)d_in[1];
    const float* conv_w = (const float*)d_in[2];
    const float* att_s  = (const float*)d_in[3];
    const float* att_d  = (const float*)d_in[4];
    const float* conv_b = (const float*)d_in[5];
    const float* proj_w = (const float*)d_in[6];
    const float* proj_b = (const float*)d_in[7];
    const float* skip_w = (const float*)d_in[8];
    const float* skip_b = (const float*)d_in[9];
    float* out = (float*)d_out;

    char* ws = (char*)d_ws;
    size_t o = 0;
    auto alloc = [&](size_t b) { size_t c = o; o += (b + 255) & ~(size_t)255; return c; };
    unsigned short* cwb  = (unsigned short*)(ws + alloc((size_t)2 * HIDDEN * HD * 2));
    unsigned short* pwb  = (unsigned short*)(ws + alloc((size_t)2 * HIDDEN * HIDDEN * 2));
    unsigned short* swb  = (unsigned short*)(ws + alloc((size_t)2 * HIDDEN * HIDDEN * 2));
    unsigned char* h8    = (unsigned char*)(ws + alloc((size_t)N_NODES * HD));
    float* a_src         = (float*)(ws + alloc((size_t)N_NODES * HEADS * 4));
    float* a_dst         = (float*)(ws + alloc((size_t)N_NODES * HEADS * 4));
    int* row_ptr         = (int*)(ws + alloc((size_t)(N_NODES + 1) * 4));
    int* src_s           = (int*)(ws + alloc((size_t)N_EDGES * 4));
    __hip_bfloat16* rc   = (__hip_bfloat16*)(ws + alloc((size_t)N_NODES * HIDDEN * 2));
    __hip_bfloat16* xb   = (__hip_bfloat16*)(ws + alloc((size_t)N_NODES * HIDDEN * 2));
    int* bh              = (int*)(ws + alloc((size_t)NBH * 4));

    // tmp (packed bucketed edges, 3.2 MB) aliases rc (12.8 MB): rc is first written
    // by msg_k, strictly after sortB_k consumed tmp. Stream-ordered, no race.
    unsigned* tmp = (unsigned*)rc;

    const int* srcp = ei;
    const int* dstp = ei + N_EDGES;

    prep_k<<<SWZ_B + NBLK_H, 256, 0, stream>>>(
        conv_w, proj_w, skip_w, cwb, pwb, swb, dstp, bh);

    // fused: gemmc layer-0 reading fp32 x (blocks 0-511) + scatter (blocks 512-609)
    gemmcsc_k<<<GEMM_BLKS + NBLK_H, 256, 0, stream>>>(
        x, cwb, att_s, att_d, h8, a_src, a_dst, NTILES,
        srcp, dstp, bh, tmp);
    sortB_k<<<NBUCK, 256, 0, stream>>>(tmp, bh, src_s, row_ptr);

    // layer 0 message + proj/skip (skip input = fp32 x, cast in-kernel)
    msg_k<<<(N_NODES / 2 + 3) / 4, 256, 0, stream>>>(
        row_ptr, src_s, a_src, a_dst, h8, conv_b, rc);
    gemmp_k<__hip_bfloat16, true><<<512, 256, 0, stream>>>(
        rc, pwb, x, swb, proj_b, skip_b, xb, NTILES);

    // layer 1 (all-bf16 inputs)
    gemmc_k<<<512, 256, 0, stream>>>(
        xb, cwb + (size_t)HIDDEN * HD,
        att_s + HD, att_d + HD, h8, a_src, a_dst, NTILES);
    msg_k<<<(N_NODES / 2 + 3) / 4, 256, 0, stream>>>(
        row_ptr, src_s, a_src, a_dst, h8, conv_b + HIDDEN, rc);
    gemmp_k<float, false><<<512, 256, 0, stream>>>(
        rc, pwb + (size_t)HIDDEN * HIDDEN,
        xb, swb + (size_t)HIDDEN * HIDDEN,
        proj_b + HIDDEN, skip_b + HIDDEN, out, NTILES);
}

// Round 9
// 314.189 us; speedup vs baseline: 1.0152x; 1.0152x over previous
//
#include <hip/hip_runtime.h>
#include <hip/hip_bf16.h>
#include <stdint.h>

#define N_NODES 50000
#define N_EDGES 800000
#define HIDDEN  128
#define HEADS   4
#define HD      (HEADS*HIDDEN)   // 512
#define NTILES  (N_NODES/16)         // 3125 (exact)

// ---- atomic-free CSR build geometry ----
#define NBUCK   196                  // ceil(50000/256) buckets of dst>>8
#define TILE_H  8192                 // edges per hist/scatter block
#define NBLK_H  ((N_EDGES + TILE_H - 1) / TILE_H)   // 98
#define NBH     (NBUCK * NBLK_H)     // 19208 count-matrix entries
#define SWZ_N   196608               // weight-swizzle thread range
#define SWZ_B   (SWZ_N / 256)        // 768 swizzle blocks; hist blocks follow
#define GEMM_BLKS 512                // gemmc blocks in the fused l0 dispatch

typedef __attribute__((ext_vector_type(8))) short  short8;
typedef __attribute__((ext_vector_type(4))) float  floatx4;
typedef __attribute__((ext_vector_type(2))) float  floatx2;

static __device__ __forceinline__ unsigned short bf16_bits(float f) {
    __hip_bfloat16 h = __float2bfloat16(f);
    union { __hip_bfloat16 b; unsigned short s; } u; u.b = h; return u.s;
}

// leaky_relu(a, 0.2) == max(a, 0.2a); then fast exp
static __device__ __forceinline__ float lexp(float a) {
    return __expf(fmaxf(a, 0.2f * a));
}

// pack 8 fp32 -> short8 of bf16 bits (RTNE, bit-identical to the old prep cast)
static __device__ __forceinline__ short8 packbf8(float4 a, float4 b) {
    short8 s;
    s[0] = (short)bf16_bits(a.x); s[1] = (short)bf16_bits(a.y);
    s[2] = (short)bf16_bits(a.z); s[3] = (short)bf16_bits(a.w);
    s[4] = (short)bf16_bits(b.x); s[5] = (short)bf16_bits(b.y);
    s[6] = (short)bf16_bits(b.z); s[7] = (short)bf16_bits(b.w);
    return s;
}

// ---------------- fp8 e4m3 encode/decode (HW cvt when available) ----------------

#if __has_builtin(__builtin_amdgcn_cvt_pk_fp8_f32) && __has_builtin(__builtin_amdgcn_cvt_pk_f32_fp8)
#define FP8_HW 1
#else
#define FP8_HW 0
static __device__ __forceinline__ unsigned fp8_enc1(float f) {
    unsigned s = __float_as_uint(f) >> 31;
    float a = fabsf(f);
    if (a < 0.0009765625f) return s << 7;
    if (a > 448.f) a = 448.f;
    unsigned ub = __float_as_uint(a) + 0x00080000u;  // round at bit19
    int e = (int)((ub >> 23) & 255) - 120;           // biased-7 exponent
    unsigned m = (ub >> 20) & 7;
    if (e <= 0) {
        int mm = (int)(a * 512.f + 0.5f); if (mm > 7) mm = 7;
        return (s << 7) | (unsigned)mm;
    }
    if (e > 15) { e = 15; m = 7; }
    return (s << 7) | ((unsigned)e << 3) | m;
}
static __device__ __forceinline__ floatx2 fp8_dec_pk(unsigned b2) {
    floatx2 r;
    unsigned b = b2 & 255;
    {
        unsigned s = (b >> 7) & 1, e = (b >> 3) & 15, m = b & 7;
        r.x = (e == 0) ? ((s ? -1.f : 1.f) * (float)m * 0.001953125f)
                       : __uint_as_float((s << 31) | ((e + 120) << 23) | (m << 20));
    }
    b = (b2 >> 8) & 255;
    {
        unsigned s = (b >> 7) & 1, e = (b >> 3) & 15, m = b & 7;
        r.y = (e == 0) ? ((s ? -1.f : 1.f) * (float)m * 0.001953125f)
                       : __uint_as_float((s << 31) | ((e + 120) << 23) | (m << 20));
    }
    return r;
}
#endif

static __device__ __forceinline__ unsigned fp8_pack4(float a, float b, float c, float d) {
#if FP8_HW
    int w = __builtin_amdgcn_cvt_pk_fp8_f32(a, b, 0, false);
    w     = __builtin_amdgcn_cvt_pk_fp8_f32(c, d, w, true);
    return (unsigned)w;
#else
    return fp8_enc1(a) | (fp8_enc1(b) << 8) | (fp8_enc1(c) << 16) | (fp8_enc1(d) << 24);
#endif
}

// packed accumulate: acc2[0..3] += w * decode8(u)   (floatx2 math -> v_pk_fma_f32)
static __device__ __forceinline__ void accf8p(floatx2* acc2, uint2 u, float wt) {
    floatx2 wv = {wt, wt};
#if FP8_HW
    acc2[0] += wv * __builtin_amdgcn_cvt_pk_f32_fp8((int)u.x, false);
    acc2[1] += wv * __builtin_amdgcn_cvt_pk_f32_fp8((int)u.x, true);
    acc2[2] += wv * __builtin_amdgcn_cvt_pk_f32_fp8((int)u.y, false);
    acc2[3] += wv * __builtin_amdgcn_cvt_pk_f32_fp8((int)u.y, true);
#else
    acc2[0] += wv * fp8_dec_pk(u.x);
    acc2[1] += wv * fp8_dec_pk(u.x >> 16);
    acc2[2] += wv * fp8_dec_pk(u.y);
    acc2[3] += wv * fp8_dec_pk(u.y >> 16);
#endif
}

// ---------------- prep: weight swizzle + bucket histogram (x-cast ELIMINATED) ----------------
// GEMMs read fp32 x directly (each row consumed once; cast-in-kernel is bit-identical).
// blocks [0, SWZ_B): weight swizzle; [SWZ_B, SWZ_B+NBLK_H): per-block LDS histogram of
// dst>>8, RAW counts to bh[bucket*NBLK_H + blk] (bin-major).
// proj_w rows PERMUTED (kr -> (kr&7)*16 + (kr>>3)) to compensate rc's [r][ntl] layout.

__global__ __launch_bounds__(256) void prep_k(
        const float* __restrict__ conv_w, const float* __restrict__ proj_w,
        const float* __restrict__ skip_w,
        unsigned short* __restrict__ cwb, unsigned short* __restrict__ pwb,
        unsigned short* __restrict__ swb,
        const int* __restrict__ dst, int* __restrict__ bh) {
    __shared__ int hh[NBUCK];
    if (blockIdx.x >= SWZ_B) {                   // block-uniform branch: syncthreads safe
        int blk = blockIdx.x - SWZ_B;
        for (int c = threadIdx.x; c < NBUCK; c += 256) hh[c] = 0;
        __syncthreads();
        int e0 = blk * TILE_H;
#pragma unroll
        for (int i = 0; i < TILE_H / 256; ++i) {
            int e = e0 + threadIdx.x + i * 256;
            if (e < N_EDGES) atomicAdd(&hh[dst[e] >> 8], 1);
        }
        __syncthreads();
        for (int c = threadIdx.x; c < NBUCK; c += 256) bh[c * NBLK_H + blk] = hh[c];
        return;
    }
    int o = blockIdx.x * 256 + threadIdx.x;
    const float* B; unsigned short* D; int off, N; bool perm = false;
    if (o < 131072)      { B = conv_w + (o >> 16) * 65536; D = cwb + (o >> 16) * 65536; off = o & 65535; N = 512; }
    else if (o < 163840) { int t = o - 131072; B = proj_w + (t >> 14) * 16384; D = pwb + (t >> 14) * 16384; off = t & 16383; N = 128; perm = true; }
    else                 { int t = o - 163840; B = skip_w + (t >> 14) * 16384; D = swb + (t >> 14) * 16384; off = t & 16383; N = 128; }
    int j = off & 7, r = (off >> 3) & 15, q = (off >> 7) & 3;
    int rest = off >> 9, ntn = N >> 4;
    int nt = rest % ntn, kc = rest / ntn;
    int kr = kc * 32 + q * 8 + j;
    int row = perm ? ((kr & 7) * 16 + (kr >> 3)) : kr;
    D[off] = bf16_bits(B[(size_t)row * N + nt * 16 + r]);
}

// ---------------- gemmc body (templated A dtype; shared by plain and fused-l0) ---------------
// h8 row layout (bytes): [head][r][ntl]; natural channel ntl*16+r at byte r*8+ntl of head slice.

template <bool F32A>
static __device__ __forceinline__ void gemmc_body(
        const void* __restrict__ A, const unsigned short* __restrict__ Bs,
        const float* __restrict__ att_s, const float* __restrict__ att_d,
        unsigned char* __restrict__ h8,
        float* __restrict__ a_src, float* __restrict__ a_dst,
        int mtiles, int bid, int stride) {
    int head = threadIdx.x >> 6;
    int lane = threadIdx.x & 63;
    int r = lane & 15, q = lane >> 4;

    short8 Bf[4][8];
#pragma unroll
    for (int kc = 0; kc < 4; ++kc)
#pragma unroll
        for (int ntl = 0; ntl < 8; ++ntl)
            Bf[kc][ntl] = *(const short8*)((const short*)Bs +
                (((size_t)(kc * 32 + head * 8 + ntl) * 4 + q) * 128 + r * 8));

    float as_r[8], ad_r[8];
#pragma unroll
    for (int ntl = 0; ntl < 8; ++ntl) {
        as_r[ntl] = att_s[head * HIDDEN + ntl * 16 + r];
        ad_r[ntl] = att_d[head * HIDDEN + ntl * 16 + r];
    }

    auto loadA = [&](int mtv, short8* dstv) {
        if constexpr (F32A) {
            const float* Ab = (const float*)A + (size_t)(mtv * 16 + r) * HIDDEN + q * 8;
#pragma unroll
            for (int kc = 0; kc < 4; ++kc) {
                float4 v0 = *(const float4*)(Ab + kc * 32);
                float4 v1 = *(const float4*)(Ab + kc * 32 + 4);
                dstv[kc] = packbf8(v0, v1);
            }
        } else {
            const short* Ab = (const short*)A + (size_t)(mtv * 16 + r) * HIDDEN + q * 8;
#pragma unroll
            for (int kc = 0; kc < 4; ++kc) dstv[kc] = *(const short8*)(Ab + kc * 32);
        }
    };

    int mt = bid;
    short8 av[4];
    if (mt < mtiles) loadA(mt, av);
    while (mt < mtiles) {
        int nmt = mt + stride;
        short8 avn[4];
        if (nmt < mtiles) loadA(nmt, avn);
        int m0 = mt * 16;
        floatx4 acc[8];
#pragma unroll
        for (int i = 0; i < 8; ++i) acc[i] = (floatx4){0.f, 0.f, 0.f, 0.f};
#pragma unroll
        for (int kc = 0; kc < 4; ++kc)
#pragma unroll
            for (int ntl = 0; ntl < 8; ++ntl)
                acc[ntl] = __builtin_amdgcn_mfma_f32_16x16x32_bf16(av[kc], Bf[kc][ntl], acc[ntl], 0, 0, 0);

        // store h8: row q*4+i, 8 B per row per lane
#pragma unroll
        for (int i = 0; i < 4; ++i) {
            uint2 o;
            o.x = fp8_pack4(acc[0][i], acc[1][i], acc[2][i], acc[3][i]);
            o.y = fp8_pack4(acc[4][i], acc[5][i], acc[6][i], acc[7][i]);
            *(uint2*)(h8 + (size_t)(m0 + q * 4 + i) * HD + head * HIDDEN + r * 8) = o;
        }
        // fused alpha (fp32 accumulators — full precision)
        float sA[4] = {0, 0, 0, 0}, sD[4] = {0, 0, 0, 0};
#pragma unroll
        for (int ntl = 0; ntl < 8; ++ntl)
#pragma unroll
            for (int i = 0; i < 4; ++i) {
                sA[i] += acc[ntl][i] * as_r[ntl];
                sD[i] += acc[ntl][i] * ad_r[ntl];
            }
#pragma unroll
        for (int d = 1; d < 16; d <<= 1)
#pragma unroll
            for (int i = 0; i < 4; ++i) {
                sA[i] += __shfl_xor(sA[i], d);
                sD[i] += __shfl_xor(sD[i], d);
            }
        if (r == 0)
#pragma unroll
            for (int i = 0; i < 4; ++i) {
                int row = m0 + q * 4 + i;
                a_src[row * HEADS + head] = sA[i];
                a_dst[row * HEADS + head] = sD[i];
            }
        mt = nmt;
#pragma unroll
        for (int kc = 0; kc < 4; ++kc) av[kc] = avn[kc];
    }
}

__global__ __launch_bounds__(256, 2) void gemmc_k(
        const __hip_bfloat16* __restrict__ A, const unsigned short* __restrict__ Bs,
        const float* __restrict__ att_s, const float* __restrict__ att_d,
        unsigned char* __restrict__ h8,
        float* __restrict__ a_src, float* __restrict__ a_dst, int mtiles) {
    gemmc_body<false>(A, Bs, att_s, att_d, h8, a_src, a_dst, mtiles, blockIdx.x, gridDim.x);
}

// ---------------- fused gemmc-l0 (fp32 A) + scatterA (block-range split) ----------------
// blocks [0, GEMM_BLKS): gemmc reading x fp32 directly.
// blocks [GEMM_BLKS, GEMM_BLKS+NBLK_H): scatter, with redundant scan of RAW bh.

__global__ __launch_bounds__(256, 2) void gemmcsc_k(
        const float* __restrict__ A, const unsigned short* __restrict__ Bs,
        const float* __restrict__ att_s, const float* __restrict__ att_d,
        unsigned char* __restrict__ h8,
        float* __restrict__ a_src, float* __restrict__ a_dst, int mtiles,
        const int* __restrict__ src, const int* __restrict__ dst,
        const int* __restrict__ bh, unsigned* __restrict__ tmp) {
    __shared__ int cnt[256], scanbuf[256];
    if (blockIdx.x < GEMM_BLKS) {
        gemmc_body<true>(A, Bs, att_s, att_d, h8, a_src, a_dst, mtiles, blockIdx.x, GEMM_BLKS);
        return;
    }
    int blk = blockIdx.x - GEMM_BLKS;
    int t = threadIdx.x;
    // redundant scan: thread t owns bucket t (t < NBUCK)
    int Tt = 0, Pt = 0;
    if (t < NBUCK) {
        const int* row = bh + (size_t)t * NBLK_H;
        for (int i = 0; i < NBLK_H; ++i) {
            int v = row[i];
            Tt += v;
            Pt += (i < blk) ? v : 0;
        }
    }
    scanbuf[t] = Tt;
    __syncthreads();
    for (int off = 1; off < 256; off <<= 1) {
        int xv = (t >= off) ? scanbuf[t - off] : 0;
        __syncthreads();
        scanbuf[t] += xv;
        __syncthreads();
    }
    int excl = scanbuf[t] - Tt;           // bucket base (exclusive over buckets)
    if (t < NBUCK) cnt[t] = excl + Pt;    // + within-bucket prefix for this block
    __syncthreads();
    int e0 = blk * TILE_H;
#pragma unroll
    for (int i = 0; i < TILE_H / 256; ++i) {
        int e = e0 + t + i * 256;
        if (e < N_EDGES) {
            int d = dst[e];
            int pos = atomicAdd(&cnt[d >> 8], 1);
            tmp[pos] = ((unsigned)(d & 255) << 16) | (unsigned)src[e];
        }
    }
}

// ---------------- sortB: per-bucket low-byte counting sort + row_ptr ----------------
// One block per bucket. Bucket bases recomputed redundantly from RAW bh.

__global__ __launch_bounds__(256) void sortB_k(const unsigned* __restrict__ tmp,
                                               const int* __restrict__ bh,
                                               int* __restrict__ src_sorted,
                                               int* __restrict__ row_ptr) {
    __shared__ int cnt[256], buf[256], pos[256], bbase[256], btot[256];
    int t = threadIdx.x, b = blockIdx.x;
    // redundant bucket-base scan from raw counts
    int Tt = 0;
    if (t < NBUCK) {
        const int* row = bh + (size_t)t * NBLK_H;
        for (int i = 0; i < NBLK_H; ++i) Tt += row[i];
    }
    buf[t] = Tt;
    __syncthreads();
    for (int off = 1; off < 256; off <<= 1) {
        int xv = (t >= off) ? buf[t - off] : 0;
        __syncthreads();
        buf[t] += xv;
        __syncthreads();
    }
    bbase[t] = buf[t] - Tt;
    btot[t]  = Tt;
    __syncthreads();
    int beg = bbase[b];
    int end = beg + btot[b];
    // low-byte counting sort within bucket
    cnt[t] = 0;
    __syncthreads();
    for (int i = beg + t; i < end; i += 256) atomicAdd(&cnt[(tmp[i] >> 16) & 255], 1);
    __syncthreads();
    int v = cnt[t];
    buf[t] = v;
    __syncthreads();
    for (int off = 1; off < 256; off <<= 1) {
        int xv = (t >= off) ? buf[t - off] : 0;
        __syncthreads();
        buf[t] += xv;
        __syncthreads();
    }
    int excl = buf[t] - v;
    int d = b * 256 + t;
    if (d <= N_NODES) row_ptr[d] = beg + excl;   // d==N_NODES lands on beg+full = N_EDGES
    pos[t] = excl;
    __syncthreads();
    for (int i = beg + t; i < end; i += 256) {
        unsigned w = tmp[i];
        int c = (w >> 16) & 255;
        int p = beg + atomicAdd(&pos[c], 1);
        src_sorted[p] = (int)(w & 0xFFFFu);
    }
}

// ---------------- proj+skip dual GEMM: B-in-regs, A/A2 prefetch; A2 optionally fp32 --------

template <typename OutT, bool F32A2>
__global__ __launch_bounds__(256, 2) void gemmp_k(
        const __hip_bfloat16* __restrict__ A,  const unsigned short* __restrict__ Bs,
        const void* __restrict__ A2, const unsigned short* __restrict__ Bs2,
        const float* __restrict__ b1, const float* __restrict__ b2,
        OutT* __restrict__ D, int mtiles) {
    int wave = threadIdx.x >> 6;
    int lane = threadIdx.x & 63;
    int r = lane & 15, q = lane >> 4;
    int nh = wave & 1;

    short8 Bf[4][4], Bf2[4][4];
#pragma unroll
    for (int kc = 0; kc < 4; ++kc)
#pragma unroll
        for (int ntl = 0; ntl < 4; ++ntl) {
            size_t off = (((size_t)(kc * 8 + nh * 4 + ntl) * 4 + q) * 128 + r * 8);
            Bf[kc][ntl]  = *(const short8*)((const short*)Bs  + off);
            Bf2[kc][ntl] = *(const short8*)((const short*)Bs2 + off);
        }
    float bias[4];
#pragma unroll
    for (int ntl = 0; ntl < 4; ++ntl) {
        int col = nh * 64 + ntl * 16 + r;
        bias[ntl] = b1[col] + b2[col];
    }

    auto loadA = [&](int mtv, short8* d1, short8* d2) {
        const short* Ab = (const short*)A + (size_t)(mtv * 16 + r) * HIDDEN + q * 8;
#pragma unroll
        for (int kc = 0; kc < 4; ++kc) d1[kc] = *(const short8*)(Ab + kc * 32);
        if constexpr (F32A2) {
            const float* Ab2 = (const float*)A2 + (size_t)(mtv * 16 + r) * HIDDEN + q * 8;
#pragma unroll
            for (int kc = 0; kc < 4; ++kc) {
                float4 v0 = *(const float4*)(Ab2 + kc * 32);
                float4 v1 = *(const float4*)(Ab2 + kc * 32 + 4);
                d2[kc] = packbf8(v0, v1);
            }
        } else {
            const short* Ab2 = (const short*)A2 + (size_t)(mtv * 16 + r) * HIDDEN + q * 8;
#pragma unroll
            for (int kc = 0; kc < 4; ++kc) d2[kc] = *(const short8*)(Ab2 + kc * 32);
        }
    };

    const int stride = gridDim.x * 2;
    int mt = blockIdx.x * 2 + (wave >> 1);
    short8 av[4], av2[4];
    if (mt < mtiles) loadA(mt, av, av2);
    while (mt < mtiles) {
        int nmt = mt + stride;
        short8 avn[4], avn2[4];
        if (nmt < mtiles) loadA(nmt, avn, avn2);
        int m0 = mt * 16;
        floatx4 acc[4];
#pragma unroll
        for (int i = 0; i < 4; ++i) acc[i] = (floatx4){0.f, 0.f, 0.f, 0.f};
#pragma unroll
        for (int kc = 0; kc < 4; ++kc)
#pragma unroll
            for (int ntl = 0; ntl < 4; ++ntl) {
                acc[ntl] = __builtin_amdgcn_mfma_f32_16x16x32_bf16(av[kc],  Bf[kc][ntl],  acc[ntl], 0, 0, 0);
                acc[ntl] = __builtin_amdgcn_mfma_f32_16x16x32_bf16(av2[kc], Bf2[kc][ntl], acc[ntl], 0, 0, 0);
            }
#pragma unroll
        for (int ntl = 0; ntl < 4; ++ntl) {
            int col = nh * 64 + ntl * 16 + r;
#pragma unroll
            for (int i = 0; i < 4; ++i) {
                int row = m0 + q * 4 + i;
                float v = acc[ntl][i] + bias[ntl];
                if constexpr (sizeof(OutT) == 4)
                    ((float*)D)[(size_t)row * HIDDEN + col] = v;
                else
                    ((__hip_bfloat16*)D)[(size_t)row * HIDDEN + col] = __float2bfloat16(v);
            }
        }
        mt = nmt;
#pragma unroll
        for (int kc = 0; kc < 4; ++kc) { av[kc] = avn[kc]; av2[kc] = avn2[kc]; }
    }
}

// ---------------- fused softmax + aggregation: one wave per node (PROVEN FLOOR) ----------------
// Round-0 structure, measured 60.1-60.8 us across rounds 0/5/7: 4-edge groups,
// wave-uniform edge ids via readlane (SALU broadcast), 8 B/lane dwordx2 gathers.
// Structural variants tested and REJECTED: 8-deep unroll (r2: serialized at VGPR cap),
// lane-split pairs (r1: bpermute in critical path), dual-node chains (r8: halves
// device-level wave count -> fewer outstanding requests). Do not restructure.

__global__ __launch_bounds__(256) void msg_k(const int* __restrict__ row_ptr,
                                             const int* __restrict__ src_sorted,
                                             const float* __restrict__ a_src,
                                             const float* __restrict__ a_dst,
                                             const unsigned char* __restrict__ h8,
                                             const float* __restrict__ conv_b,
                                             __hip_bfloat16* __restrict__ rc) {
    int wave = threadIdx.x >> 6;
    int lane = threadIdx.x & 63;
    int n = blockIdx.x * 4 + wave;
    if (n >= N_NODES) return;
    int head = lane >> 4;
    float adn = a_dst[n * HEADS + head];
    int beg = row_ptr[n], end = row_ptr[n + 1];
    const uint2* hq = (const uint2*)h8;

    floatx2 acc2[4];
#pragma unroll
    for (int k = 0; k < 4; ++k) acc2[k] = (floatx2){0.f, 0.f};
    float esum = 0.f;
    for (int base = beg; base < end; base += 32) {
        int m = min(32, end - base);
        int sv = (lane < m) ? src_sorted[base + lane] : 0;
        int j = 0;
        for (; j + 4 <= m; j += 4) {
            int s0 = __builtin_amdgcn_readlane(sv, j);
            int s1 = __builtin_amdgcn_readlane(sv, j + 1);
            int s2 = __builtin_amdgcn_readlane(sv, j + 2);
            int s3 = __builtin_amdgcn_readlane(sv, j + 3);
            uint2 u0 = hq[(size_t)s0 * 64 + lane];
            uint2 u1 = hq[(size_t)s1 * 64 + lane];
            uint2 u2 = hq[(size_t)s2 * 64 + lane];
            uint2 u3 = hq[(size_t)s3 * 64 + lane];
            float e0 = lexp(a_src[s0 * 4 + head] + adn);
            float e1 = lexp(a_src[s1 * 4 + head] + adn);
            float e2 = lexp(a_src[s2 * 4 + head] + adn);
            float e3 = lexp(a_src[s3 * 4 + head] + adn);
            accf8p(acc2, u0, e0);
            accf8p(acc2, u1, e1);
            accf8p(acc2, u2, e2);
            accf8p(acc2, u3, e3);
            esum += (e0 + e1) + (e2 + e3);
        }
        for (; j < m; ++j) {
            int s0 = __builtin_amdgcn_readlane(sv, j);
            uint2 u0 = hq[(size_t)s0 * 64 + lane];
            float e0 = lexp(a_src[s0 * 4 + head] + adn);
            accf8p(acc2, u0, e0);
            esum += e0;
        }
    }
    float rinv = 1.f / (esum + 1e-16f);
    float acc[8];
#pragma unroll
    for (int k = 0; k < 4; ++k) { acc[2 * k] = acc2[k].x * rinv; acc[2 * k + 1] = acc2[k].y * rinv; }
#pragma unroll
    for (int k = 0; k < 8; ++k) {
        acc[k] += __shfl_xor(acc[k], 16);
        acc[k] += __shfl_xor(acc[k], 32);
    }
    if (lane < 16) {
        // lane holds natural channels {k*16+lane}; rc written permuted [r][ntl]
        union { uint4 v; unsigned short us[8]; } o;
#pragma unroll
        for (int k = 0; k < 8; ++k) {
            float mres = 0.25f * acc[k] + conv_b[k * 16 + lane];
            o.us[k] = bf16_bits(mres > 0.f ? mres : 0.f);
        }
        ((uint4*)rc)[(size_t)n * 16 + lane] = o.v;
    }
}

// ---------------- launcher ----------------

extern "C" void kernel_launch(void* const* d_in, const int* in_sizes, int n_in,
                              void* d_out, int out_size, void* d_ws, size_t ws_size,
                              hipStream_t stream) {
    const float* x      = (const float*)d_in[0];
    const int*   ei     = (const int*)d_in[1];
    const float* conv_w = (const float*)d_in[2];
    const float* att_s  = (const float*)d_in[3];
    const float* att_d  = (const float*)d_in[4];
    const float* conv_b = (const float*)d_in[5];
    const float* proj_w = (const float*)d_in[6];
    const float* proj_b = (const float*)d_in[7];
    const float* skip_w = (const float*)d_in[8];
    const float* skip_b = (const float*)d_in[9];
    float* out = (float*)d_out;

    char* ws = (char*)d_ws;
    size_t o = 0;
    auto alloc = [&](size_t b) { size_t c = o; o += (b + 255) & ~(size_t)255; return c; };
    unsigned short* cwb  = (unsigned short*)(ws + alloc((size_t)2 * HIDDEN * HD * 2));
    unsigned short* pwb  = (unsigned short*)(ws + alloc((size_t)2 * HIDDEN * HIDDEN * 2));
    unsigned short* swb  = (unsigned short*)(ws + alloc((size_t)2 * HIDDEN * HIDDEN * 2));
    unsigned char* h8    = (unsigned char*)(ws + alloc((size_t)N_NODES * HD));
    float* a_src         = (float*)(ws + alloc((size_t)N_NODES * HEADS * 4));
    float* a_dst         = (float*)(ws + alloc((size_t)N_NODES * HEADS * 4));
    int* row_ptr         = (int*)(ws + alloc((size_t)(N_NODES + 1) * 4));
    int* src_s           = (int*)(ws + alloc((size_t)N_EDGES * 4));
    __hip_bfloat16* rc   = (__hip_bfloat16*)(ws + alloc((size_t)N_NODES * HIDDEN * 2));
    __hip_bfloat16* xb   = (__hip_bfloat16*)(ws + alloc((size_t)N_NODES * HIDDEN * 2));
    int* bh              = (int*)(ws + alloc((size_t)NBH * 4));

    // tmp (packed bucketed edges, 3.2 MB) aliases rc (12.8 MB): rc is first written
    // by msg_k, strictly after sortB_k consumed tmp. Stream-ordered, no race.
    unsigned* tmp = (unsigned*)rc;

    const int* srcp = ei;
    const int* dstp = ei + N_EDGES;

    prep_k<<<SWZ_B + NBLK_H, 256, 0, stream>>>(
        conv_w, proj_w, skip_w, cwb, pwb, swb, dstp, bh);

    // fused: gemmc layer-0 reading fp32 x (blocks 0-511) + scatter (blocks 512-609)
    gemmcsc_k<<<GEMM_BLKS + NBLK_H, 256, 0, stream>>>(
        x, cwb, att_s, att_d, h8, a_src, a_dst, NTILES,
        srcp, dstp, bh, tmp);
    sortB_k<<<NBUCK, 256, 0, stream>>>(tmp, bh, src_s, row_ptr);

    // layer 0 message + proj/skip (skip input = fp32 x, cast in-kernel)
    msg_k<<<(N_NODES + 3) / 4, 256, 0, stream>>>(
        row_ptr, src_s, a_src, a_dst, h8, conv_b, rc);
    gemmp_k<__hip_bfloat16, true><<<512, 256, 0, stream>>>(
        rc, pwb, x, swb, proj_b, skip_b, xb, NTILES);

    // layer 1 (all-bf16 inputs)
    gemmc_k<<<512, 256, 0, stream>>>(
        xb, cwb + (size_t)HIDDEN * HD,
        att_s + HD, att_d + HD, h8, a_src, a_dst, NTILES);
    msg_k<<<(N_NODES + 3) / 4, 256, 0, stream>>>(
        row_ptr, src_s, a_src, a_dst, h8, conv_b + HIDDEN, rc);
    gemmp_k<float, false><<<512, 256, 0, stream>>>(
        rc, pwb + (size_t)HIDDEN * HIDDEN,
        xb, swb + (size_t)HIDDEN * HIDDEN,
        proj_b + HIDDEN, skip_b + HIDDEN, out, NTILES);
}